// Round 5
// baseline (856.264 us; speedup 1.0000x reference)
//
// LoFTR encoder layer — MI355X / gfx950. Round 4 (resubmit after broker timeout):
// 2-phase double-buffered GEMM (prefetch-before-compute, one barrier per K-step),
// compile-time K, tiled weight-prep transpose. f9/dwconv/attn/kv unchanged from R3.
#include <hip/hip_runtime.h>
#include <stdint.h>

#define LL 19200
#define NBATCH 4
#define NROWS (NBATCH * LL)   // 76800
#define HH 120
#define WW 160

typedef short bhalf8 __attribute__((ext_vector_type(8)));
typedef float f32x4 __attribute__((ext_vector_type(4)));

__device__ __forceinline__ float bfbits2f(uint32_t u) { union { uint32_t i; float f; } c; c.i = u << 16; return c.f; }
__device__ __forceinline__ float bf2f(uint16_t h) { return bfbits2f((uint32_t)h); }
__device__ __forceinline__ uint16_t f2bf(float f) {
    union { float f; uint32_t i; } c; c.f = f;
    return (uint16_t)((c.i + 0x7FFFu + ((c.i >> 16) & 1u)) >> 16);
}
__device__ __forceinline__ uint32_t pk2(uint16_t a, uint16_t b) { return (uint32_t)a | ((uint32_t)b << 16); }
__device__ __forceinline__ float elup1(float x) { return x > 0.f ? x + 1.f : expf(x); } // elu(x)+1

__device__ __forceinline__ uint4 pack8f(const float* p) {
    float4 lo = *(const float4*)p; float4 hi = *(const float4*)(p + 4);
    uint4 s;
    s.x = pk2(f2bf(lo.x), f2bf(lo.y)); s.y = pk2(f2bf(lo.z), f2bf(lo.w));
    s.z = pk2(f2bf(hi.x), f2bf(hi.y)); s.w = pk2(f2bf(hi.z), f2bf(hi.w));
    return s;
}

// async global->LDS, 16B per lane; lds dst is wave-uniform base (lane*16 added by HW)
__device__ __forceinline__ void gll16(const void* g, void* l) {
    __builtin_amdgcn_global_load_lds((const __attribute__((address_space(1))) uint32_t*)g,
                                     (__attribute__((address_space(3))) uint32_t*)l, 16, 0, 0);
}

// ---------------- weight prep: tiled transpose f32[K][N] -> bf16[N][K] ----------------
// 172 blocks, one 64x64 tile each; coalesced reads + LDS transpose + coalesced writes.
__global__ __launch_bounds__(256)
void prep_all(const float* __restrict__ Wq, const float* __restrict__ Wk,
              const float* __restrict__ Wv, const float* __restrict__ Wm,
              const float* __restrict__ Wm1, const float* __restrict__ Wm2,
              const float* __restrict__ Wd, const float* __restrict__ Wu,
              uint16_t* __restrict__ wq, uint16_t* __restrict__ wk,
              uint16_t* __restrict__ wvv, uint16_t* __restrict__ wm,
              uint16_t* __restrict__ wm1, uint16_t* __restrict__ wm2,
              uint16_t* __restrict__ wd, uint16_t* __restrict__ wu) {
    __shared__ float ts[64][65];
    const int tid = threadIdx.x;
    int blk = blockIdx.x;
    const float* s; uint16_t* d; int K, N, t;
    if (blk < 64)        { int w = blk >> 4; t = blk & 15;
                           s = w == 0 ? Wq : w == 1 ? Wk : w == 2 ? Wv : Wm;
                           d = w == 0 ? wq : w == 1 ? wk : w == 2 ? wvv : wm;
                           K = 256; N = 256; }
    else if (blk < 128)  { s = Wm1; d = wm1; K = 512; N = 512; t = blk - 64; }
    else if (blk < 160)  { s = Wm2; d = wm2; K = 512; N = 256; t = blk - 128; }
    else if (blk < 168)  { s = Wd;  d = wd;  K = 512; N = 64;  t = blk - 160; }
    else                 { s = Wu;  d = wu;  K = 64;  N = 256; t = blk - 168; }
    const int ntk = K >> 6;
    const int tn = t / ntk, tk = t - tn * ntk;
    const int c = tid & 63, r4 = tid >> 6;
#pragma unroll
    for (int i = 0; i < 16; ++i) {
        int r = r4 * 16 + i;
        ts[r][c] = s[(long)(tk * 64 + r) * N + tn * 64 + c];
    }
    __syncthreads();
#pragma unroll
    for (int i = 0; i < 16; ++i) {
        int rr = r4 * 16 + i;
        d[(long)(tn * 64 + rr) * K + tk * 64 + c] = f2bf(ts[c][rr]);
    }
}

// ---------------- 128xBN MFMA GEMM, 512 threads, 8 waves, 2-phase double-buffer --------
// MODE_A: 0 = bf16 A0b stride K; 1 = f32 A0f stride K (optional bf16 sideout);
//         2 = concat f32 A0f(256) | bf16 A1b(256); 3 = concat bf16 A0b | bf16 A1b
#define EPI_NONE 0
#define EPI_RELU 1
#define EPI_LN 2
#define EPI_FINAL 3

template<int BN, int K, int MODE_A, int EPI>
__global__ __launch_bounds__(512)
void gemm_big(const float* __restrict__ A0f, const uint16_t* __restrict__ A0b,
              const uint16_t* __restrict__ A1b,
              const uint16_t* __restrict__ Wt,
              uint16_t* __restrict__ outb, float* __restrict__ outf, int outW,
              uint16_t* __restrict__ sideout,
              const float* __restrict__ lnw, const float* __restrict__ lnb,
              const float* __restrict__ xres, const uint16_t* __restrict__ xresb,
              const uint16_t* __restrict__ msg2res,
              const uint16_t* __restrict__ convres, const float* __restrict__ ratep)
{
    constexpr int WCOLS = BN / 64;            // 4 (BN=256) or 1 (BN=64)
    constexpr int WROWS = 8 / WCOLS;          // 2 or 8
    constexpr int MT = 128 / (WROWS * 16);    // 4 or 1
    constexpr int ASZ = 128 * 32;             // elems per A buffer
    constexpr int BSZ = BN * 32;
    __shared__ __align__(16) uint16_t a_sm[2 * ASZ];
    __shared__ __align__(16) uint16_t b_sm[2 * BSZ];
    const int tid = threadIdx.x;
    const int lane = tid & 63;
    const int wv = tid >> 6;
    const int wr = wv / WCOLS, wc = wv % WCOLS;
    const long row0 = (long)blockIdx.x * 128;
    const int col0 = blockIdx.y * BN;
    const int l15 = lane & 15, lk = lane >> 4;

    f32x4 acc[MT][4];
#pragma unroll
    for (int m = 0; m < MT; ++m)
#pragma unroll
        for (int n = 0; n < 4; ++n) acc[m][n] = (f32x4){0.f, 0.f, 0.f, 0.f};

    const int sr = tid >> 2;          // 0..127
    const int sc = (tid & 3) * 8;     // 0,8,16,24
    const long argA = row0 + sr;

    auto stageAB = [&](int buf, int k0) {
        uint16_t* ab = a_sm + buf * ASZ;
        uint16_t* bb = b_sm + buf * BSZ;
        if (MODE_A == 0) {
            gll16(A0b + argA * (long)K + k0 + sc, ab + wv * 512);
        } else if (MODE_A == 1) {
            uint4 stg = pack8f(A0f + argA * (long)K + k0 + sc);
            *(uint4*)&ab[sr * 32 + sc] = stg;
            if (sideout) *(uint4*)(sideout + argA * (long)K + k0 + sc) = stg;
        } else if (MODE_A == 2) {
            if (k0 < 256) *(uint4*)&ab[sr * 32 + sc] = pack8f(A0f + argA * 256 + k0 + sc);
            else          gll16(A1b + argA * 256 + (k0 - 256) + sc, ab + wv * 512);
        } else {
            const uint16_t* srcp = (k0 < 256) ? (A0b + argA * 256 + k0 + sc)
                                              : (A1b + argA * 256 + (k0 - 256) + sc);
            gll16(srcp, ab + wv * 512);
        }
        if (BN == 256) {
            gll16(Wt + (long)(col0 + sr) * K + k0 + sc, bb + wv * 512);
            gll16(Wt + (long)(col0 + 128 + sr) * K + k0 + sc, bb + 4096 + wv * 512);
        } else {
            if (tid < 256) gll16(Wt + (long)(col0 + sr) * K + k0 + sc, bb + wv * 512);
        }
    };

    auto comp = [&](int buf) {
        const uint16_t* ab = a_sm + buf * ASZ;
        const uint16_t* bb = b_sm + buf * BSZ;
        bhalf8 af[MT];
#pragma unroll
        for (int m = 0; m < MT; ++m)
            af[m] = *(const bhalf8*)&ab[(wr * MT * 16 + m * 16 + l15) * 32 + lk * 8];
#pragma unroll
        for (int n = 0; n < 4; ++n) {
            bhalf8 bfr = *(const bhalf8*)&bb[(wc * 64 + n * 16 + l15) * 32 + lk * 8];
#pragma unroll
            for (int m = 0; m < MT; ++m)
                acc[m][n] = __builtin_amdgcn_mfma_f32_16x16x32_bf16(af[m], bfr, acc[m][n], 0, 0, 0);
        }
    };

    // 2-phase pipeline: stage(next) issued BEFORE comp(cur); one barrier per step.
    stageAB(0, 0);
    __syncthreads();
    int cur = 0;
#pragma unroll
    for (int k0 = 32; k0 < K; k0 += 32) {
        stageAB(cur ^ 1, k0);
        comp(cur);
        __syncthreads();      // drains vmcnt/lgkm for buffer cur^1; frees cur for restage
        cur ^= 1;
    }
    comp(cur);

    const int cl = l15;
    const int rg4 = lk * 4;

    if constexpr (EPI == EPI_LN) {
        __shared__ float red_s[4][128];
        __shared__ float red_ss[4][128];
#pragma unroll
        for (int m = 0; m < MT; ++m)
#pragma unroll
            for (int j = 0; j < 4; ++j) {
                float p = 0.f, pp = 0.f;
#pragma unroll
                for (int n = 0; n < 4; ++n) { float v = acc[m][n][j]; p += v; pp += v * v; }
#pragma unroll
                for (int msk = 1; msk < 16; msk <<= 1) { p += __shfl_xor(p, msk, 64); pp += __shfl_xor(pp, msk, 64); }
                if (cl == 0) {
                    int lr = wr * 64 + m * 16 + rg4 + j;
                    red_s[wc][lr] = p; red_ss[wc][lr] = pp;
                }
            }
        __syncthreads();
#pragma unroll
        for (int m = 0; m < MT; ++m)
#pragma unroll
            for (int j = 0; j < 4; ++j) {
                int lr = wr * 64 + m * 16 + rg4 + j;
                float s = red_s[0][lr] + red_s[1][lr] + red_s[2][lr] + red_s[3][lr];
                float ss = red_ss[0][lr] + red_ss[1][lr] + red_ss[2][lr] + red_ss[3][lr];
                float mu = s * (1.f / 256.f);
                float var = ss * (1.f / 256.f) - mu * mu;
                float rstd = rsqrtf(var + 1e-5f);
                long rowg = row0 + lr;
#pragma unroll
                for (int n = 0; n < 4; ++n) {
                    int col = wc * 64 + n * 16 + cl;
                    float vv = (acc[m][n][j] - mu) * rstd * lnw[col] + lnb[col];
                    outb[rowg * (long)outW + col] = f2bf(vv);
                }
            }
    } else if constexpr (EPI == EPI_FINAL) {
        float rate = ratep[0];
#pragma unroll
        for (int m = 0; m < MT; ++m)
#pragma unroll
            for (int j = 0; j < 4; ++j) {
                long rowg = row0 + wr * MT * 16 + m * 16 + rg4 + j;
                int bb2 = (int)(rowg / LL);
                int ll = (int)(rowg - (long)bb2 * LL);
#pragma unroll
                for (int n = 0; n < 4; ++n) {
                    int col = wc * 64 + n * 16 + cl;
                    long o = rowg * 256 + col;
                    float xv = xresb ? bf2f(xresb[o]) : xres[o];
                    float m2 = bf2f(msg2res[o]);
                    float cv = bf2f(convres[((long)(bb2 * 256 + col)) * LL + ll]);
                    outf[o] = xv + m2 + 0.1f * acc[m][n][j] + rate * cv;
                }
            }
    } else {
#pragma unroll
        for (int m = 0; m < MT; ++m)
#pragma unroll
            for (int j = 0; j < 4; ++j) {
                long rowg = row0 + wr * MT * 16 + m * 16 + rg4 + j;
#pragma unroll
                for (int n = 0; n < 4; ++n) {
                    int col = col0 + wc * 64 + n * 16 + cl;
                    float vv = acc[m][n][j];
                    if (EPI == EPI_RELU) vv = vv > 0.f ? vv : 0.f;
                    outb[rowg * (long)outW + col] = f2bf(vv);
                }
            }
    }
}

// ---------------- linear attention: stage 1 partial KV / Ksum ----------------
__global__ __launch_bounds__(256)
void kv_partial(const uint16_t* __restrict__ kb, const uint16_t* __restrict__ vb,
                float* __restrict__ part) {
    __shared__ float kf_sm[32][33];
    __shared__ float v_sm[32][36];
    const int tid = threadIdx.x;
    const int bh = blockIdx.y, b = bh >> 3, h = bh & 7;
    const int s0 = blockIdx.x * 256;
    const int d = tid >> 3, vg = tid & 7;
    const int sl = tid >> 3, e4 = (tid & 7) * 4;
    float a0 = 0.f, a1 = 0.f, a2 = 0.f, a3 = 0.f, aKs = 0.f;
    for (int it = 0; it < 8; ++it) {
        long base = ((long)(b * LL + s0 + it * 32 + sl)) * 256 + h * 32 + e4;
        uint2 kk = *(const uint2*)(kb + base);
        uint2 vv = *(const uint2*)(vb + base);
        kf_sm[sl][e4 + 0] = elup1(bfbits2f(kk.x & 0xFFFFu));
        kf_sm[sl][e4 + 1] = elup1(bfbits2f(kk.x >> 16));
        kf_sm[sl][e4 + 2] = elup1(bfbits2f(kk.y & 0xFFFFu));
        kf_sm[sl][e4 + 3] = elup1(bfbits2f(kk.y >> 16));
        float4 vf;
        vf.x = bfbits2f(vv.x & 0xFFFFu); vf.y = bfbits2f(vv.x >> 16);
        vf.z = bfbits2f(vv.y & 0xFFFFu); vf.w = bfbits2f(vv.y >> 16);
        *(float4*)&v_sm[sl][e4] = vf;
        __syncthreads();
#pragma unroll 8
        for (int s = 0; s < 32; ++s) {
            float kf = kf_sm[s][d];
            aKs += kf;
            float4 v4 = *(const float4*)&v_sm[s][vg * 4];
            a0 += kf * v4.x; a1 += kf * v4.y; a2 += kf * v4.z; a3 += kf * v4.w;
        }
        __syncthreads();
    }
    long pb = ((long)(blockIdx.x * 32 + bh)) * 1056;
    part[pb + d * 32 + vg * 4 + 0] = a0;
    part[pb + d * 32 + vg * 4 + 1] = a1;
    part[pb + d * 32 + vg * 4 + 2] = a2;
    part[pb + d * 32 + vg * 4 + 3] = a3;
    if (vg == 0) part[pb + 1024 + d] = aKs;
}

__global__ __launch_bounds__(256)
void kv_final(const float* __restrict__ part, float* __restrict__ KVg, float* __restrict__ Ksum) {
    const int bh = blockIdx.x, tid = threadIdx.x;
    for (int idx = tid; idx < 1056; idx += 256) {
        float s = 0.f;
        for (int c = 0; c < 75; ++c) s += part[((long)(c * 32 + bh)) * 1056 + idx];
        if (idx < 1024) KVg[bh * 1024 + idx] = s;
        else Ksum[bh * 32 + idx - 1024] = s;
    }
}

// ---------------- attn message via MFMA: msg = (Qf @ KV_h) * Z ----------------
__global__ __launch_bounds__(256)
void attn_mfma(const uint16_t* __restrict__ qb, const float* __restrict__ KVg,
               const float* __restrict__ Ksum, uint16_t* __restrict__ msgout) {
    const int tid = threadIdx.x;
    const int lane = tid & 63;
    const int wv = tid >> 6;
    const long l0 = (long)blockIdx.x * 64;
    const int b = (int)(l0 / LL);
    const int l15 = lane & 15, lk = lane >> 4;
#pragma unroll
    for (int hi = 0; hi < 2; ++hi) {
        const int h = wv * 2 + hi;
        const float* kvb = KVg + ((long)(b * 8 + h)) * 1024;
        const float* ksb = Ksum + (b * 8 + h) * 32;
        bhalf8 B0, B1;
        float ks[8];
#pragma unroll
        for (int i = 0; i < 8; ++i) {
            int k = lk * 8 + i;
            B0[i] = (short)f2bf(kvb[k * 32 + l15]);
            B1[i] = (short)f2bf(kvb[k * 32 + 16 + l15]);
            ks[i] = ksb[k];
        }
#pragma unroll
        for (int rt = 0; rt < 4; ++rt) {
            long row = l0 + rt * 16 + l15;
            uint4 qv = *(const uint4*)(qb + row * 256 + h * 32 + lk * 8);
            float qf[8];
            qf[0] = elup1(bfbits2f(qv.x & 0xFFFFu)); qf[1] = elup1(bfbits2f(qv.x >> 16));
            qf[2] = elup1(bfbits2f(qv.y & 0xFFFFu)); qf[3] = elup1(bfbits2f(qv.y >> 16));
            qf[4] = elup1(bfbits2f(qv.z & 0xFFFFu)); qf[5] = elup1(bfbits2f(qv.z >> 16));
            qf[6] = elup1(bfbits2f(qv.w & 0xFFFFu)); qf[7] = elup1(bfbits2f(qv.w >> 16));
            bhalf8 A;
#pragma unroll
            for (int i = 0; i < 8; ++i) A[i] = (short)f2bf(qf[i]);
            float p = qf[0]*ks[0] + qf[1]*ks[1] + qf[2]*ks[2] + qf[3]*ks[3]
                    + qf[4]*ks[4] + qf[5]*ks[5] + qf[6]*ks[6] + qf[7]*ks[7];
            p += __shfl_xor(p, 16, 64);
            p += __shfl_xor(p, 32, 64);
            f32x4 d0 = (f32x4){0.f,0.f,0.f,0.f}, d1 = (f32x4){0.f,0.f,0.f,0.f};
            d0 = __builtin_amdgcn_mfma_f32_16x16x32_bf16(A, B0, d0, 0, 0, 0);
            d1 = __builtin_amdgcn_mfma_f32_16x16x32_bf16(A, B1, d1, 0, 0, 0);
#pragma unroll
            for (int j = 0; j < 4; ++j) {
                int orl = lk * 4 + j;
                float zr = __shfl(p, orl, 64);
                float Z = 1.f / (zr + 1e-6f);
                long orow = l0 + rt * 16 + orl;
                msgout[orow * 256 + h * 32 + l15]      = f2bf(d0[j] * Z);
                msgout[orow * 256 + h * 32 + 16 + l15] = f2bf(d1[j] * Z);
            }
        }
    }
}

// ---------------- conv branch: f9 1x1 projection (24 -> 9 per (l, d')) ----------------
__global__ __launch_bounds__(256)
void f9_kernel(const uint16_t* __restrict__ qb, const uint16_t* __restrict__ kb,
               const uint16_t* __restrict__ vb, const float* __restrict__ fcw,
               const float* __restrict__ fcb, uint16_t* __restrict__ fconv) {
    __shared__ __align__(16) uint16_t sm[3 * 32 * 256];
    char* smb = (char*)sm;
    const int tid = threadIdx.x;
    const int b = blockIdx.y;
    const int l0 = blockIdx.x * 32;
    for (int idx = tid; idx < 3072; idx += 256) {
        int tsr = idx >> 10, row = (idx >> 5) & 31, c = idx & 31;
        const uint16_t* src = tsr == 0 ? qb : (tsr == 1 ? kb : vb);
        uint4 v = *(const uint4*)(src + ((long)(b * LL + l0 + row)) * 256 + c * 8);
        int boff = (c * 16) ^ ((row & 7) << 4);
        *(uint4*)(smb + (tsr * 32 + row) * 512 + boff) = v;
    }
    __syncthreads();
    const int li = tid & 31, g = tid >> 5;
    float acc[9][4];
#pragma unroll
    for (int o = 0; o < 9; ++o) {
        float bv = fcb[o];
#pragma unroll
        for (int j = 0; j < 4; ++j) acc[o][j] = bv;
    }
    const int swz = (li & 7) << 4;
#pragma unroll
    for (int h = 0; h < 8; ++h) {
        float f[3][4];
#pragma unroll
        for (int s = 0; s < 3; ++s) {
            int boff = (h * 64 + g * 8) ^ swz;
            uint2 r = *(const uint2*)(smb + (s * 32 + li) * 512 + boff);
            f[s][0] = bfbits2f(r.x & 0xFFFFu); f[s][1] = bfbits2f(r.x >> 16);
            f[s][2] = bfbits2f(r.y & 0xFFFFu); f[s][3] = bfbits2f(r.y >> 16);
        }
#pragma unroll
        for (int o = 0; o < 9; ++o) {
            float w0 = fcw[o * 24 + 3 * h + 0];
            float w1 = fcw[o * 24 + 3 * h + 1];
            float w2 = fcw[o * 24 + 3 * h + 2];
#pragma unroll
            for (int j = 0; j < 4; ++j)
                acc[o][j] += w0 * f[0][j] + w1 * f[1][j] + w2 * f[2][j];
        }
    }
    const long ob = (long)(b * 288) * LL + l0 + li;
#pragma unroll
    for (int j = 0; j < 4; ++j) {
        int dp = g * 4 + j;
#pragma unroll
        for (int o = 0; o < 9; ++o)
            fconv[ob + (long)(dp * 9 + o) * LL] = f2bf(acc[o][j]);
    }
}

// ---------------- depthwise-grouped 3x3 conv, register-tiled ----------------
__global__ __launch_bounds__(256)
void dwconv2(const uint16_t* __restrict__ fconv, const float* __restrict__ depw,
             const float* __restrict__ depb, uint16_t* __restrict__ convout) {
    __shared__ __align__(16) uint16_t in_sm[9][26][48];
    __shared__ float w_sm[8][81];
    __shared__ float b_sm2[8];
    const int tid = threadIdx.x;
    const int bg = blockIdx.z, b = bg >> 5, g = bg & 31;
    const int y0 = blockIdx.y * 24;
    const int x0 = blockIdx.x * 32;
    for (int idx = tid; idx < 648; idx += 256)
        w_sm[idx / 81][idx % 81] = depw[(long)(g * 8) * 81 + idx];
    if (tid < 8) b_sm2[tid] = depb[g * 8 + tid];
    for (int rIdx = tid; rIdx < 234; rIdx += 256) {
        int i = rIdx / 26, r = rIdx - i * 26;
        int yy = y0 + r - 1;
        uint16_t* dst = &in_sm[i][r][0];
        if (yy >= 0 && yy < HH) {
            const uint16_t* rp = fconv + ((long)(b * 288 + g * 9 + i)) * LL + yy * WW;
            *(uint4*)&dst[8]  = *(const uint4*)(rp + x0);
            *(uint4*)&dst[16] = *(const uint4*)(rp + x0 + 8);
            *(uint4*)&dst[24] = *(const uint4*)(rp + x0 + 16);
            *(uint4*)&dst[32] = *(const uint4*)(rp + x0 + 24);
            dst[7]  = (x0 > 0) ? rp[x0 - 1] : (uint16_t)0;
            dst[40] = (x0 + 32 < WW) ? rp[x0 + 32] : (uint16_t)0;
        } else {
            uint4 z = {0, 0, 0, 0};
            *(uint4*)&dst[8] = z; *(uint4*)&dst[16] = z;
            *(uint4*)&dst[24] = z; *(uint4*)&dst[32] = z;
            dst[7] = 0; dst[40] = 0;
        }
    }
    __syncthreads();
    const int xi = tid & 7, m = (tid >> 3) & 7, ys = tid >> 6;
    float acc[6][4];
    float bias = b_sm2[m];
#pragma unroll
    for (int r = 0; r < 6; ++r)
#pragma unroll
        for (int o = 0; o < 4; ++o) acc[r][o] = bias;
    for (int i = 0; i < 9; ++i) {
        float w[9];
#pragma unroll
        for (int t = 0; t < 9; ++t) w[t] = w_sm[m][i * 9 + t];
#pragma unroll
        for (int rr = 0; rr < 8; ++rr) {
            const uint16_t* rowb = &in_sm[i][ys * 6 + rr][4 + xi * 4];
            uint2 lo = *(const uint2*)rowb;
            uint2 hi = *(const uint2*)(rowb + 4);
            uint32_t ex = *(const uint32_t*)(rowb + 8);
            float f[6];
            f[0] = bfbits2f(lo.y >> 16);
            f[1] = bfbits2f(hi.x & 0xFFFFu);
            f[2] = bfbits2f(hi.x >> 16);
            f[3] = bfbits2f(hi.y & 0xFFFFu);
            f[4] = bfbits2f(hi.y >> 16);
            f[5] = bfbits2f(ex & 0xFFFFu);
#pragma unroll
            for (int ky = 0; ky < 3; ++ky) {
                int ro = rr - ky;
                if (ro >= 0 && ro < 6) {
#pragma unroll
                    for (int o = 0; o < 4; ++o)
                        acc[ro][o] += w[ky * 3 + 0] * f[o] + w[ky * 3 + 1] * f[o + 1] + w[ky * 3 + 2] * f[o + 2];
                }
            }
        }
    }
    long chbase = ((long)(b * 256 + g * 8 + m)) * LL;
#pragma unroll
    for (int rl = 0; rl < 6; ++rl) {
        int y = y0 + ys * 6 + rl;
        uint2 st;
        st.x = pk2(f2bf(acc[rl][0]), f2bf(acc[rl][1]));
        st.y = pk2(f2bf(acc[rl][2]), f2bf(acc[rl][3]));
        *(uint2*)(convout + chbase + (long)y * WW + x0 + xi * 4) = st;
    }
}

// ---------------- launcher ----------------
extern "C" void kernel_launch(void* const* d_in, const int* in_sizes, int n_in,
                              void* d_out, int out_size, void* d_ws, size_t ws_size,
                              hipStream_t stream) {
    (void)in_sizes; (void)n_in; (void)out_size;
    const float* x      = (const float*)d_in[0];
    const float* src    = (const float*)d_in[1];
    const float* Wq     = (const float*)d_in[2];
    const float* Wk     = (const float*)d_in[3];
    const float* Wv     = (const float*)d_in[4];
    const float* Wmerge = (const float*)d_in[5];
    const float* Wmlp1  = (const float*)d_in[6];
    const float* Wmlp2  = (const float*)d_in[7];
    const float* ln1w   = (const float*)d_in[8];
    const float* ln1b   = (const float*)d_in[9];
    const float* ln2w   = (const float*)d_in[10];
    const float* ln2b   = (const float*)d_in[11];
    const float* Wdown  = (const float*)d_in[12];
    const float* Wup    = (const float*)d_in[13];
    const float* fcw    = (const float*)d_in[14];
    const float* fcb    = (const float*)d_in[15];
    const float* depw   = (const float*)d_in[16];
    const float* depb   = (const float*)d_in[17];
    const float* rate   = (const float*)d_in[18];

    char* ws = (char*)d_ws;
    const size_t SZ_NB = (size_t)NROWS * 256 * 2;
    const size_t O_Q = 0;
    const size_t O_K = SZ_NB;
    const size_t O_V = 2 * SZ_NB;
    const size_t O_FCONV = 3 * SZ_NB;
    const size_t O_CONVOUT = O_FCONV + (size_t)NBATCH * 288 * LL * 2;
    const size_t O_PART = O_CONVOUT + SZ_NB;
    const size_t O_KV = O_PART + (size_t)75 * 32 * 1056 * 4;
    const size_t O_KS = O_KV + (size_t)32 * 1024 * 4;
    const size_t O_WT = O_KS + (size_t)32 * 32 * 4;
    const size_t O_XB = O_WT + 704512 * 2 + 1024;
    const size_t O_SRCB = O_XB + SZ_NB;
    const size_t NEED = O_SRCB + SZ_NB;

    uint16_t* qB      = (uint16_t*)(ws + O_Q);
    uint16_t* kB      = (uint16_t*)(ws + O_K);
    uint16_t* vB      = (uint16_t*)(ws + O_V);
    uint16_t* fconv   = (uint16_t*)(ws + O_FCONV);
    uint16_t* convout = (uint16_t*)(ws + O_CONVOUT);
    float*    part    = (float*)(ws + O_PART);
    float*    KVg     = (float*)(ws + O_KV);
    float*    Ksg     = (float*)(ws + O_KS);
    uint16_t* wt_q    = (uint16_t*)(ws + O_WT);
    uint16_t* wt_k    = wt_q + 256 * 256;
    uint16_t* wt_v    = wt_k + 256 * 256;
    uint16_t* wt_m    = wt_v + 256 * 256;
    uint16_t* wt_m1   = wt_m + 256 * 256;
    uint16_t* wt_m2   = wt_m1 + 512 * 512;
    uint16_t* wt_d    = wt_m2 + 512 * 256;
    uint16_t* wt_u    = wt_d + 512 * 64;
    uint16_t* xb      = (uint16_t*)(ws + O_XB);
    uint16_t* srcb    = (uint16_t*)(ws + O_SRCB);
    // aliases (lifetimes vs launch order):
    uint16_t* msgattn = kB;
    uint16_t* msgB    = vB;
    uint16_t* hidden  = qB;
    uint16_t* msg2    = fconv;
    uint16_t* h2      = (uint16_t*)(ws + O_PART);

    const bool big = ws_size >= NEED;

    prep_all<<<172, 256, 0, stream>>>(Wq, Wk, Wv, Wmerge, Wmlp1, Wmlp2, Wdown, Wup,
                                      wt_q, wt_k, wt_v, wt_m, wt_m1, wt_m2, wt_d, wt_u);

    const dim3 g600(NROWS / 128, 1);
    // --- QKV (Q/K also emit bf16 copies of x/src when workspace allows) ---
    gemm_big<256, 256, 1, EPI_NONE><<<g600, 512, 0, stream>>>(x, nullptr, nullptr, wt_q, qB, nullptr, 256,
        big ? xb : nullptr, nullptr, nullptr, nullptr, nullptr, nullptr, nullptr, nullptr);
    gemm_big<256, 256, 1, EPI_NONE><<<g600, 512, 0, stream>>>(src, nullptr, nullptr, wt_k, kB, nullptr, 256,
        big ? srcb : nullptr, nullptr, nullptr, nullptr, nullptr, nullptr, nullptr, nullptr);
    if (big) {
        gemm_big<256, 256, 0, EPI_NONE><<<g600, 512, 0, stream>>>(nullptr, srcb, nullptr, wt_v, vB, nullptr, 256,
            nullptr, nullptr, nullptr, nullptr, nullptr, nullptr, nullptr, nullptr);
    } else {
        gemm_big<256, 256, 1, EPI_NONE><<<g600, 512, 0, stream>>>(src, nullptr, nullptr, wt_v, vB, nullptr, 256,
            nullptr, nullptr, nullptr, nullptr, nullptr, nullptr, nullptr, nullptr);
    }
    // --- linear attention KV reduce ---
    kv_partial<<<dim3(75, 32), 256, 0, stream>>>(kB, vB, part);
    kv_final<<<32, 256, 0, stream>>>(part, KVg, Ksg);
    // --- conv branch ---
    f9_kernel<<<dim3(LL / 32, NBATCH), 256, 0, stream>>>(qB, kB, vB, fcw, fcb, fconv);
    dwconv2<<<dim3(5, 5, 128), 256, 0, stream>>>(fconv, depw, depb, convout);
    // --- attention message (MFMA; overwrites kB) ---
    attn_mfma<<<NROWS / 64, 256, 0, stream>>>(qB, KVg, Ksg, msgattn);
    // --- merge + LN1 ---
    gemm_big<256, 256, 0, EPI_LN><<<g600, 512, 0, stream>>>(nullptr, msgattn, nullptr, wt_m, msgB, nullptr, 256,
        nullptr, ln1w, ln1b, nullptr, nullptr, nullptr, nullptr, nullptr);
    // --- MLP1 + relu ---
    if (big) {
        gemm_big<256, 512, 3, EPI_RELU><<<dim3(NROWS / 128, 2), 512, 0, stream>>>(nullptr, xb, msgB, wt_m1, hidden, nullptr, 512,
            nullptr, nullptr, nullptr, nullptr, nullptr, nullptr, nullptr, nullptr);
    } else {
        gemm_big<256, 512, 2, EPI_RELU><<<dim3(NROWS / 128, 2), 512, 0, stream>>>(x, nullptr, msgB, wt_m1, hidden, nullptr, 512,
            nullptr, nullptr, nullptr, nullptr, nullptr, nullptr, nullptr, nullptr);
    }
    // --- MLP2 + LN2 ---
    gemm_big<256, 512, 0, EPI_LN><<<g600, 512, 0, stream>>>(nullptr, hidden, nullptr, wt_m2, msg2, nullptr, 256,
        nullptr, ln2w, ln2b, nullptr, nullptr, nullptr, nullptr, nullptr);
    // --- adapter down + relu ---
    if (big) {
        gemm_big<64, 512, 3, EPI_RELU><<<g600, 512, 0, stream>>>(nullptr, xb, msg2, wt_d, h2, nullptr, 64,
            nullptr, nullptr, nullptr, nullptr, nullptr, nullptr, nullptr, nullptr);
    } else {
        gemm_big<64, 512, 2, EPI_RELU><<<g600, 512, 0, stream>>>(x, nullptr, msg2, wt_d, h2, nullptr, 64,
            nullptr, nullptr, nullptr, nullptr, nullptr, nullptr, nullptr, nullptr);
    }
    // --- adapter up + final combine ---
    gemm_big<256, 64, 0, EPI_FINAL><<<g600, 512, 0, stream>>>(nullptr, h2, nullptr, wt_u, nullptr, (float*)d_out, 256,
        nullptr, nullptr, nullptr, x, big ? xb : nullptr, msg2, convout, rate);
}

// Round 6
// 825.358 us; speedup vs baseline: 1.0374x; 1.0374x over previous
//
// LoFTR encoder layer — MI355X / gfx950. Round 6: counted-vmcnt 2-buffer pipeline
// (stage -> vmcnt(3) -> barrier -> comp -> barrier; loads in flight across barriers),
// dedicated f32->bf16 convert (all hot GEMMs pure global_load_lds), LDS-staged
// coalesced C-stores (kills RFO over-fetch), MLP1 grid swizzle for A-row L2 reuse.
#include <hip/hip_runtime.h>
#include <stdint.h>

#define LL 19200
#define NBATCH 4
#define NROWS (NBATCH * LL)   // 76800
#define HH 120
#define WW 160

typedef short bhalf8 __attribute__((ext_vector_type(8)));
typedef float f32x4 __attribute__((ext_vector_type(4)));

__device__ __forceinline__ float bfbits2f(uint32_t u) { union { uint32_t i; float f; } c; c.i = u << 16; return c.f; }
__device__ __forceinline__ float bf2f(uint16_t h) { return bfbits2f((uint32_t)h); }
__device__ __forceinline__ uint16_t f2bf(float f) {
    union { float f; uint32_t i; } c; c.f = f;
    return (uint16_t)((c.i + 0x7FFFu + ((c.i >> 16) & 1u)) >> 16);
}
__device__ __forceinline__ uint32_t pk2(uint16_t a, uint16_t b) { return (uint32_t)a | ((uint32_t)b << 16); }
__device__ __forceinline__ float elup1(float x) { return x > 0.f ? x + 1.f : expf(x); } // elu(x)+1

__device__ __forceinline__ uint4 pack8f(const float* p) {
    float4 lo = *(const float4*)p; float4 hi = *(const float4*)(p + 4);
    uint4 s;
    s.x = pk2(f2bf(lo.x), f2bf(lo.y)); s.y = pk2(f2bf(lo.z), f2bf(lo.w));
    s.z = pk2(f2bf(hi.x), f2bf(hi.y)); s.w = pk2(f2bf(hi.z), f2bf(hi.w));
    return s;
}

// async global->LDS, 16B per lane; lds dst is wave-uniform base (lane*16 added by HW)
__device__ __forceinline__ void gll16(const void* g, void* l) {
    __builtin_amdgcn_global_load_lds((const __attribute__((address_space(1))) uint32_t*)g,
                                     (__attribute__((address_space(3))) uint32_t*)l, 16, 0, 0);
}

__device__ __forceinline__ void barrier_raw() {
    asm volatile("" ::: "memory");
    __builtin_amdgcn_s_barrier();
    asm volatile("" ::: "memory");
}

// ---------------- f32 -> bf16 convert (x, src) ----------------
__global__ __launch_bounds__(256)
void conv_bf16(const float* __restrict__ a, const float* __restrict__ b,
               uint16_t* __restrict__ oa, uint16_t* __restrict__ ob) {
    const float* s = blockIdx.y ? b : a;
    uint16_t* d = blockIdx.y ? ob : oa;
    long i = ((long)blockIdx.x * 256 + threadIdx.x) * 16;
    *(uint4*)(d + i)     = pack8f(s + i);
    *(uint4*)(d + i + 8) = pack8f(s + i + 8);
}

// ---------------- weight prep: tiled transpose f32[K][N] -> bf16[N][K] ----------------
__global__ __launch_bounds__(256)
void prep_all(const float* __restrict__ Wq, const float* __restrict__ Wk,
              const float* __restrict__ Wv, const float* __restrict__ Wm,
              const float* __restrict__ Wm1, const float* __restrict__ Wm2,
              const float* __restrict__ Wd, const float* __restrict__ Wu,
              uint16_t* __restrict__ wq, uint16_t* __restrict__ wk,
              uint16_t* __restrict__ wvv, uint16_t* __restrict__ wm,
              uint16_t* __restrict__ wm1, uint16_t* __restrict__ wm2,
              uint16_t* __restrict__ wd, uint16_t* __restrict__ wu) {
    __shared__ float ts[64][65];
    const int tid = threadIdx.x;
    int blk = blockIdx.x;
    const float* s; uint16_t* d; int K, N, t;
    if (blk < 64)        { int w = blk >> 4; t = blk & 15;
                           s = w == 0 ? Wq : w == 1 ? Wk : w == 2 ? Wv : Wm;
                           d = w == 0 ? wq : w == 1 ? wk : w == 2 ? wvv : wm;
                           K = 256; N = 256; }
    else if (blk < 128)  { s = Wm1; d = wm1; K = 512; N = 512; t = blk - 64; }
    else if (blk < 160)  { s = Wm2; d = wm2; K = 512; N = 256; t = blk - 128; }
    else if (blk < 168)  { s = Wd;  d = wd;  K = 512; N = 64;  t = blk - 160; }
    else                 { s = Wu;  d = wu;  K = 64;  N = 256; t = blk - 168; }
    const int ntk = K >> 6;
    const int tn = t / ntk, tk = t - tn * ntk;
    const int c = tid & 63, r4 = tid >> 6;
#pragma unroll
    for (int i = 0; i < 16; ++i) {
        int r = r4 * 16 + i;
        ts[r][c] = s[(long)(tk * 64 + r) * N + tn * 64 + c];
    }
    __syncthreads();
#pragma unroll
    for (int i = 0; i < 16; ++i) {
        int rr = r4 * 16 + i;
        d[(long)(tn * 64 + rr) * K + tk * 64 + c] = f2bf(ts[c][rr]);
    }
}

// ---------------- 128xBN MFMA GEMM, 512 threads, 8 waves ----------------
// MODE_A: 0 = bf16 A0b stride K; 1 = f32 A0f stride K (fallback, +sideout);
//         2 = concat f32|bf16 (fallback); 3 = concat bf16 A0b(256) | bf16 A1b(256)
// PIPE (MODE 0/3): counted-vmcnt 2-buffer pipeline. Fallback modes: __syncthreads loop.
#define EPI_NONE 0
#define EPI_RELU 1
#define EPI_LN 2
#define EPI_FINAL 3

template<int BN, int K, int MODE_A, int EPI, int COLX>
__global__ __launch_bounds__(512)
void gemm_big(const float* __restrict__ A0f, const uint16_t* __restrict__ A0b,
              const uint16_t* __restrict__ A1b,
              const uint16_t* __restrict__ Wt,
              uint16_t* __restrict__ outb, float* __restrict__ outf, int outW,
              uint16_t* __restrict__ sideout,
              const float* __restrict__ lnw, const float* __restrict__ lnb,
              const float* __restrict__ xres, const uint16_t* __restrict__ xresb,
              const uint16_t* __restrict__ msg2res,
              const uint16_t* __restrict__ convres, const float* __restrict__ ratep)
{
    constexpr int WCOLS = BN / 64;            // 4 (BN=256) or 1 (BN=64)
    constexpr int WROWS = 8 / WCOLS;          // 2 or 8
    constexpr int MT = 128 / (WROWS * 16);    // 4 or 1
    constexpr int ASZ = 128 * 32;
    constexpr int BSZ = BN * 32;
    constexpr int NSTEP = K / 32;
    constexpr bool PIPE = (MODE_A == 0 || MODE_A == 3);
    __shared__ __align__(16) uint16_t smem[2 * ASZ + 2 * BSZ];
    uint16_t* a_sm = smem;
    uint16_t* b_sm = smem + 2 * ASZ;
    const int tid = threadIdx.x;
    const int lane = tid & 63;
    const int wv = tid >> 6;
    const int wr = wv / WCOLS, wc = wv % WCOLS;
    const long row0 = (long)(COLX ? blockIdx.y : blockIdx.x) * 128;
    const int col0 = (COLX ? blockIdx.x : blockIdx.y) * BN;
    const int l15 = lane & 15, lk = lane >> 4;

    f32x4 acc[MT][4];
#pragma unroll
    for (int m = 0; m < MT; ++m)
#pragma unroll
        for (int n = 0; n < 4; ++n) acc[m][n] = (f32x4){0.f, 0.f, 0.f, 0.f};

    const int sr = tid >> 2;          // 0..127
    const int sc = (tid & 3) * 8;     // 0,8,16,24
    const long argA = row0 + sr;

    auto stageAB = [&](int buf, int k0) {
        uint16_t* ab = a_sm + buf * ASZ;
        uint16_t* bb = b_sm + buf * BSZ;
        if (MODE_A == 0) {
            gll16(A0b + argA * (long)K + k0 + sc, ab + wv * 512);
        } else if (MODE_A == 1) {
            uint4 stg = pack8f(A0f + argA * (long)K + k0 + sc);
            *(uint4*)&ab[sr * 32 + sc] = stg;
            if (sideout) *(uint4*)(sideout + argA * (long)K + k0 + sc) = stg;
        } else if (MODE_A == 2) {
            if (k0 < 256) *(uint4*)&ab[sr * 32 + sc] = pack8f(A0f + argA * 256 + k0 + sc);
            else          gll16(A1b + argA * 256 + (k0 - 256) + sc, ab + wv * 512);
        } else {
            const uint16_t* srcp = (k0 < 256) ? (A0b + argA * 256 + k0 + sc)
                                              : (A1b + argA * 256 + (k0 - 256) + sc);
            gll16(srcp, ab + wv * 512);
        }
        if (BN == 256) {
            gll16(Wt + (long)(col0 + sr) * K + k0 + sc, bb + wv * 512);
            gll16(Wt + (long)(col0 + 128 + sr) * K + k0 + sc, bb + 4096 + wv * 512);
        } else {
            if (tid < 256) gll16(Wt + (long)(col0 + sr) * K + k0 + sc, bb + wv * 512);
        }
    };

    auto comp = [&](int buf) {
        const uint16_t* ab = a_sm + buf * ASZ;
        const uint16_t* bb = b_sm + buf * BSZ;
        bhalf8 af[MT];
#pragma unroll
        for (int m = 0; m < MT; ++m)
            af[m] = *(const bhalf8*)&ab[(wr * MT * 16 + m * 16 + l15) * 32 + lk * 8];
#pragma unroll
        for (int n = 0; n < 4; ++n) {
            bhalf8 bfr = *(const bhalf8*)&bb[(wc * 64 + n * 16 + l15) * 32 + lk * 8];
#pragma unroll
            for (int m = 0; m < MT; ++m)
                acc[m][n] = __builtin_amdgcn_mfma_f32_16x16x32_bf16(af[m], bfr, acc[m][n], 0, 0, 0);
        }
    };

    if constexpr (PIPE) {
        // T4: stage(t+1) -> vmcnt(3) [tile t's loads done; t+1's stay in flight]
        // -> barrier -> comp(t) -> barrier [all waves consumed tile t before restage].
        stageAB(0, 0);
#pragma unroll
        for (int t = 0; t < NSTEP; ++t) {
            if (t + 1 < NSTEP) {
                stageAB((t + 1) & 1, (t + 1) * 32);
                if constexpr (BN == 256) {
                    asm volatile("s_waitcnt vmcnt(3)" ::: "memory");
                } else {
                    if (wv < 4) asm volatile("s_waitcnt vmcnt(2)" ::: "memory");
                    else        asm volatile("s_waitcnt vmcnt(1)" ::: "memory");
                }
            } else {
                asm volatile("s_waitcnt vmcnt(0)" ::: "memory");
            }
            barrier_raw();
            comp(t & 1);
            barrier_raw();
        }
    } else {
        stageAB(0, 0);
        __syncthreads();
        int cur = 0;
#pragma unroll
        for (int k0 = 32; k0 < K; k0 += 32) {
            stageAB(cur ^ 1, k0);
            comp(cur);
            __syncthreads();
            cur ^= 1;
        }
        comp(cur);
    }
    __syncthreads();   // LDS free for epilogue staging

    const int cl = l15;
    const int rg4 = lk * 4;

    if constexpr (EPI == EPI_FINAL) {
        // f32 output: 16 lanes x 4B = full 64B lines — direct stores, no RFO.
        float rate = ratep[0];
#pragma unroll
        for (int m = 0; m < MT; ++m)
#pragma unroll
            for (int j = 0; j < 4; ++j) {
                long rowg = row0 + wr * MT * 16 + m * 16 + rg4 + j;
                int bb2 = (int)(rowg / LL);
                int ll = (int)(rowg - (long)bb2 * LL);
#pragma unroll
                for (int n = 0; n < 4; ++n) {
                    int col = wc * 64 + n * 16 + cl;
                    long o = rowg * 256 + col;
                    float xv = xresb ? bf2f(xresb[o]) : xres[o];
                    float m2 = bf2f(msg2res[o]);
                    float cv = bf2f(convres[((long)(bb2 * 256 + col)) * LL + ll]);
                    outf[o] = xv + m2 + 0.1f * acc[m][n][j] + rate * cv;
                }
            }
        return;
    }

    float mu_r[MT][4], rs_r[MT][4];
    float lw[4], lb[4];
    if constexpr (EPI == EPI_LN) {
        float* red_s  = (float*)smem;            // [4][128], 2KB
        float* red_ss = red_s + 512;             // 2KB
#pragma unroll
        for (int m = 0; m < MT; ++m)
#pragma unroll
            for (int j = 0; j < 4; ++j) {
                float p = 0.f, pp = 0.f;
#pragma unroll
                for (int n = 0; n < 4; ++n) { float v = acc[m][n][j]; p += v; pp += v * v; }
#pragma unroll
                for (int msk = 1; msk < 16; msk <<= 1) { p += __shfl_xor(p, msk, 64); pp += __shfl_xor(pp, msk, 64); }
                if (cl == 0) {
                    int lr = wr * 64 + m * 16 + rg4 + j;
                    red_s[wc * 128 + lr] = p; red_ss[wc * 128 + lr] = pp;
                }
            }
        __syncthreads();
#pragma unroll
        for (int m = 0; m < MT; ++m)
#pragma unroll
            for (int j = 0; j < 4; ++j) {
                int lr = wr * 64 + m * 16 + rg4 + j;
                float s  = red_s[lr] + red_s[128 + lr] + red_s[256 + lr] + red_s[384 + lr];
                float ss = red_ss[lr] + red_ss[128 + lr] + red_ss[256 + lr] + red_ss[384 + lr];
                float mu = s * (1.f / 256.f);
                float var = ss * (1.f / 256.f) - mu * mu;
                mu_r[m][j] = mu;
                rs_r[m][j] = rsqrtf(var + 1e-5f);
            }
#pragma unroll
        for (int n = 0; n < 4; ++n) {
            lw[n] = lnw[wc * 64 + n * 16 + cl];
            lb[n] = lnb[wc * 64 + n * 16 + cl];
        }
        __syncthreads();   // red arrays consumed before stg may alias
    }

    // ---- staged coalesced bf16 store: frag -> LDS chunk -> dwordx4 rows ----
    constexpr int CST = BN + 8;
    uint16_t* stg = (EPI == EPI_LN) ? (smem + 2048) : smem;   // LN: skip red region
    constexpr int ROWS = (BN == 256) ? 32 : 128;              // rows per chunk
    constexpr int GPR = BN / 8;                               // 8-elem groups per row
#pragma unroll
    for (int m = 0; m < MT; ++m) {
        __syncthreads();
#pragma unroll
        for (int j = 0; j < 4; ++j) {
            int lr = wr * 16 + rg4 + j;     // BN=256: 0..31; BN=64: 0..127
#pragma unroll
            for (int n = 0; n < 4; ++n) {
                float v = acc[m][n][j];
                if constexpr (EPI == EPI_RELU) v = v > 0.f ? v : 0.f;
                if constexpr (EPI == EPI_LN)   v = (v - mu_r[m][j]) * rs_r[m][j] * lw[n] + lb[n];
                stg[lr * CST + wc * 64 + n * 16 + cl] = f2bf(v);
            }
        }
        __syncthreads();
#pragma unroll
        for (int it = 0; it < (ROWS * GPR + 511) / 512; ++it) {
            int flat = it * 512 + tid;
            if (flat < ROWS * GPR) {
                int lr = flat / GPR, g = flat % GPR;
                long grow = (BN == 256) ? (row0 + (lr >> 4) * 64 + m * 16 + (lr & 15))
                                        : (row0 + lr);
                *(uint4*)(outb + grow * (long)outW + col0 + g * 8) = *(const uint4*)&stg[lr * CST + g * 8];
            }
        }
    }
}

// ---------------- linear attention: stage 1 partial KV / Ksum ----------------
__global__ __launch_bounds__(256)
void kv_partial(const uint16_t* __restrict__ kb, const uint16_t* __restrict__ vb,
                float* __restrict__ part) {
    __shared__ float kf_sm[32][33];
    __shared__ float v_sm[32][36];
    const int tid = threadIdx.x;
    const int bh = blockIdx.y, b = bh >> 3, h = bh & 7;
    const int s0 = blockIdx.x * 256;
    const int d = tid >> 3, vg = tid & 7;
    const int sl = tid >> 3, e4 = (tid & 7) * 4;
    float a0 = 0.f, a1 = 0.f, a2 = 0.f, a3 = 0.f, aKs = 0.f;
    for (int it = 0; it < 8; ++it) {
        long base = ((long)(b * LL + s0 + it * 32 + sl)) * 256 + h * 32 + e4;
        uint2 kk = *(const uint2*)(kb + base);
        uint2 vv = *(const uint2*)(vb + base);
        kf_sm[sl][e4 + 0] = elup1(bfbits2f(kk.x & 0xFFFFu));
        kf_sm[sl][e4 + 1] = elup1(bfbits2f(kk.x >> 16));
        kf_sm[sl][e4 + 2] = elup1(bfbits2f(kk.y & 0xFFFFu));
        kf_sm[sl][e4 + 3] = elup1(bfbits2f(kk.y >> 16));
        float4 vf;
        vf.x = bfbits2f(vv.x & 0xFFFFu); vf.y = bfbits2f(vv.x >> 16);
        vf.z = bfbits2f(vv.y & 0xFFFFu); vf.w = bfbits2f(vv.y >> 16);
        *(float4*)&v_sm[sl][e4] = vf;
        __syncthreads();
#pragma unroll 8
        for (int s = 0; s < 32; ++s) {
            float kf = kf_sm[s][d];
            aKs += kf;
            float4 v4 = *(const float4*)&v_sm[s][vg * 4];
            a0 += kf * v4.x; a1 += kf * v4.y; a2 += kf * v4.z; a3 += kf * v4.w;
        }
        __syncthreads();
    }
    long pb = ((long)(blockIdx.x * 32 + bh)) * 1056;
    part[pb + d * 32 + vg * 4 + 0] = a0;
    part[pb + d * 32 + vg * 4 + 1] = a1;
    part[pb + d * 32 + vg * 4 + 2] = a2;
    part[pb + d * 32 + vg * 4 + 3] = a3;
    if (vg == 0) part[pb + 1024 + d] = aKs;
}

__global__ __launch_bounds__(256)
void kv_final(const float* __restrict__ part, float* __restrict__ KVg, float* __restrict__ Ksum) {
    const int bh = blockIdx.x, tid = threadIdx.x;
    for (int idx = tid; idx < 1056; idx += 256) {
        float s = 0.f;
        for (int c = 0; c < 75; ++c) s += part[((long)(c * 32 + bh)) * 1056 + idx];
        if (idx < 1024) KVg[bh * 1024 + idx] = s;
        else Ksum[bh * 32 + idx - 1024] = s;
    }
}

// ---------------- attn message via MFMA: msg = (Qf @ KV_h) * Z ----------------
__global__ __launch_bounds__(256)
void attn_mfma(const uint16_t* __restrict__ qb, const float* __restrict__ KVg,
               const float* __restrict__ Ksum, uint16_t* __restrict__ msgout) {
    const int tid = threadIdx.x;
    const int lane = tid & 63;
    const int wv = tid >> 6;
    const long l0 = (long)blockIdx.x * 64;
    const int b = (int)(l0 / LL);
    const int l15 = lane & 15, lk = lane >> 4;
#pragma unroll
    for (int hi = 0; hi < 2; ++hi) {
        const int h = wv * 2 + hi;
        const float* kvb = KVg + ((long)(b * 8 + h)) * 1024;
        const float* ksb = Ksum + (b * 8 + h) * 32;
        bhalf8 B0, B1;
        float ks[8];
#pragma unroll
        for (int i = 0; i < 8; ++i) {
            int k = lk * 8 + i;
            B0[i] = (short)f2bf(kvb[k * 32 + l15]);
            B1[i] = (short)f2bf(kvb[k * 32 + 16 + l15]);
            ks[i] = ksb[k];
        }
#pragma unroll
        for (int rt = 0; rt < 4; ++rt) {
            long row = l0 + rt * 16 + l15;
            uint4 qv = *(const uint4*)(qb + row * 256 + h * 32 + lk * 8);
            float qf[8];
            qf[0] = elup1(bfbits2f(qv.x & 0xFFFFu)); qf[1] = elup1(bfbits2f(qv.x >> 16));
            qf[2] = elup1(bfbits2f(qv.y & 0xFFFFu)); qf[3] = elup1(bfbits2f(qv.y >> 16));
            qf[4] = elup1(bfbits2f(qv.z & 0xFFFFu)); qf[5] = elup1(bfbits2f(qv.z >> 16));
            qf[6] = elup1(bfbits2f(qv.w & 0xFFFFu)); qf[7] = elup1(bfbits2f(qv.w >> 16));
            bhalf8 A;
#pragma unroll
            for (int i = 0; i < 8; ++i) A[i] = (short)f2bf(qf[i]);
            float p = qf[0]*ks[0] + qf[1]*ks[1] + qf[2]*ks[2] + qf[3]*ks[3]
                    + qf[4]*ks[4] + qf[5]*ks[5] + qf[6]*ks[6] + qf[7]*ks[7];
            p += __shfl_xor(p, 16, 64);
            p += __shfl_xor(p, 32, 64);
            f32x4 d0 = (f32x4){0.f,0.f,0.f,0.f}, d1 = (f32x4){0.f,0.f,0.f,0.f};
            d0 = __builtin_amdgcn_mfma_f32_16x16x32_bf16(A, B0, d0, 0, 0, 0);
            d1 = __builtin_amdgcn_mfma_f32_16x16x32_bf16(A, B1, d1, 0, 0, 0);
#pragma unroll
            for (int j = 0; j < 4; ++j) {
                int orl = lk * 4 + j;
                float zr = __shfl(p, orl, 64);
                float Z = 1.f / (zr + 1e-6f);
                long orow = l0 + rt * 16 + orl;
                msgout[orow * 256 + h * 32 + l15]      = f2bf(d0[j] * Z);
                msgout[orow * 256 + h * 32 + 16 + l15] = f2bf(d1[j] * Z);
            }
        }
    }
}

// ---------------- conv branch: f9 1x1 projection (24 -> 9 per (l, d')) ----------------
__global__ __launch_bounds__(256)
void f9_kernel(const uint16_t* __restrict__ qb, const uint16_t* __restrict__ kb,
               const uint16_t* __restrict__ vb, const float* __restrict__ fcw,
               const float* __restrict__ fcb, uint16_t* __restrict__ fconv) {
    __shared__ __align__(16) uint16_t sm[3 * 32 * 256];
    char* smb = (char*)sm;
    const int tid = threadIdx.x;
    const int b = blockIdx.y;
    const int l0 = blockIdx.x * 32;
    for (int idx = tid; idx < 3072; idx += 256) {
        int tsr = idx >> 10, row = (idx >> 5) & 31, c = idx & 31;
        const uint16_t* src = tsr == 0 ? qb : (tsr == 1 ? kb : vb);
        uint4 v = *(const uint4*)(src + ((long)(b * LL + l0 + row)) * 256 + c * 8);
        int boff = (c * 16) ^ ((row & 7) << 4);
        *(uint4*)(smb + (tsr * 32 + row) * 512 + boff) = v;
    }
    __syncthreads();
    const int li = tid & 31, g = tid >> 5;
    float acc[9][4];
#pragma unroll
    for (int o = 0; o < 9; ++o) {
        float bv = fcb[o];
#pragma unroll
        for (int j = 0; j < 4; ++j) acc[o][j] = bv;
    }
    const int swz = (li & 7) << 4;
#pragma unroll
    for (int h = 0; h < 8; ++h) {
        float f[3][4];
#pragma unroll
        for (int s = 0; s < 3; ++s) {
            int boff = (h * 64 + g * 8) ^ swz;
            uint2 r = *(const uint2*)(smb + (s * 32 + li) * 512 + boff);
            f[s][0] = bfbits2f(r.x & 0xFFFFu); f[s][1] = bfbits2f(r.x >> 16);
            f[s][2] = bfbits2f(r.y & 0xFFFFu); f[s][3] = bfbits2f(r.y >> 16);
        }
#pragma unroll
        for (int o = 0; o < 9; ++o) {
            float w0 = fcw[o * 24 + 3 * h + 0];
            float w1 = fcw[o * 24 + 3 * h + 1];
            float w2 = fcw[o * 24 + 3 * h + 2];
#pragma unroll
            for (int j = 0; j < 4; ++j)
                acc[o][j] += w0 * f[0][j] + w1 * f[1][j] + w2 * f[2][j];
        }
    }
    const long ob = (long)(b * 288) * LL + l0 + li;
#pragma unroll
    for (int j = 0; j < 4; ++j) {
        int dp = g * 4 + j;
#pragma unroll
        for (int o = 0; o < 9; ++o)
            fconv[ob + (long)(dp * 9 + o) * LL] = f2bf(acc[o][j]);
    }
}

// ---------------- depthwise-grouped 3x3 conv, register-tiled ----------------
__global__ __launch_bounds__(256)
void dwconv2(const uint16_t* __restrict__ fconv, const float* __restrict__ depw,
             const float* __restrict__ depb, uint16_t* __restrict__ convout) {
    __shared__ __align__(16) uint16_t in_sm[9][26][48];
    __shared__ float w_sm[8][81];
    __shared__ float b_sm2[8];
    const int tid = threadIdx.x;
    const int bg = blockIdx.z, b = bg >> 5, g = bg & 31;
    const int y0 = blockIdx.y * 24;
    const int x0 = blockIdx.x * 32;
    for (int idx = tid; idx < 648; idx += 256)
        w_sm[idx / 81][idx % 81] = depw[(long)(g * 8) * 81 + idx];
    if (tid < 8) b_sm2[tid] = depb[g * 8 + tid];
    for (int rIdx = tid; rIdx < 234; rIdx += 256) {
        int i = rIdx / 26, r = rIdx - i * 26;
        int yy = y0 + r - 1;
        uint16_t* dst = &in_sm[i][r][0];
        if (yy >= 0 && yy < HH) {
            const uint16_t* rp = fconv + ((long)(b * 288 + g * 9 + i)) * LL + yy * WW;
            *(uint4*)&dst[8]  = *(const uint4*)(rp + x0);
            *(uint4*)&dst[16] = *(const uint4*)(rp + x0 + 8);
            *(uint4*)&dst[24] = *(const uint4*)(rp + x0 + 16);
            *(uint4*)&dst[32] = *(const uint4*)(rp + x0 + 24);
            dst[7]  = (x0 > 0) ? rp[x0 - 1] : (uint16_t)0;
            dst[40] = (x0 + 32 < WW) ? rp[x0 + 32] : (uint16_t)0;
        } else {
            uint4 z = {0, 0, 0, 0};
            *(uint4*)&dst[8] = z; *(uint4*)&dst[16] = z;
            *(uint4*)&dst[24] = z; *(uint4*)&dst[32] = z;
            dst[7] = 0; dst[40] = 0;
        }
    }
    __syncthreads();
    const int xi = tid & 7, m = (tid >> 3) & 7, ys = tid >> 6;
    float acc[6][4];
    float bias = b_sm2[m];
#pragma unroll
    for (int r = 0; r < 6; ++r)
#pragma unroll
        for (int o = 0; o < 4; ++o) acc[r][o] = bias;
    for (int i = 0; i < 9; ++i) {
        float w[9];
#pragma unroll
        for (int t = 0; t < 9; ++t) w[t] = w_sm[m][i * 9 + t];
#pragma unroll
        for (int rr = 0; rr < 8; ++rr) {
            const uint16_t* rowb = &in_sm[i][ys * 6 + rr][4 + xi * 4];
            uint2 lo = *(const uint2*)rowb;
            uint2 hi = *(const uint2*)(rowb + 4);
            uint32_t ex = *(const uint32_t*)(rowb + 8);
            float f[6];
            f[0] = bfbits2f(lo.y >> 16);
            f[1] = bfbits2f(hi.x & 0xFFFFu);
            f[2] = bfbits2f(hi.x >> 16);
            f[3] = bfbits2f(hi.y & 0xFFFFu);
            f[4] = bfbits2f(hi.y >> 16);
            f[5] = bfbits2f(ex & 0xFFFFu);
#pragma unroll
            for (int ky = 0; ky < 3; ++ky) {
                int ro = rr - ky;
                if (ro >= 0 && ro < 6) {
#pragma unroll
                    for (int o = 0; o < 4; ++o)
                        acc[ro][o] += w[ky * 3 + 0] * f[o] + w[ky * 3 + 1] * f[o + 1] + w[ky * 3 + 2] * f[o + 2];
                }
            }
        }
    }
    long chbase = ((long)(b * 256 + g * 8 + m)) * LL;
#pragma unroll
    for (int rl = 0; rl < 6; ++rl) {
        int y = y0 + ys * 6 + rl;
        uint2 st;
        st.x = pk2(f2bf(acc[rl][0]), f2bf(acc[rl][1]));
        st.y = pk2(f2bf(acc[rl][2]), f2bf(acc[rl][3]));
        *(uint2*)(convout + chbase + (long)y * WW + x0 + xi * 4) = st;
    }
}

// ---------------- launcher ----------------
extern "C" void kernel_launch(void* const* d_in, const int* in_sizes, int n_in,
                              void* d_out, int out_size, void* d_ws, size_t ws_size,
                              hipStream_t stream) {
    (void)in_sizes; (void)n_in; (void)out_size;
    const float* x      = (const float*)d_in[0];
    const float* src    = (const float*)d_in[1];
    const float* Wq     = (const float*)d_in[2];
    const float* Wk     = (const float*)d_in[3];
    const float* Wv     = (const float*)d_in[4];
    const float* Wmerge = (const float*)d_in[5];
    const float* Wmlp1  = (const float*)d_in[6];
    const float* Wmlp2  = (const float*)d_in[7];
    const float* ln1w   = (const float*)d_in[8];
    const float* ln1b   = (const float*)d_in[9];
    const float* ln2w   = (const float*)d_in[10];
    const float* ln2b   = (const float*)d_in[11];
    const float* Wdown  = (const float*)d_in[12];
    const float* Wup    = (const float*)d_in[13];
    const float* fcw    = (const float*)d_in[14];
    const float* fcb    = (const float*)d_in[15];
    const float* depw   = (const float*)d_in[16];
    const float* depb   = (const float*)d_in[17];
    const float* rate   = (const float*)d_in[18];

    char* ws = (char*)d_ws;
    const size_t SZ_NB = (size_t)NROWS * 256 * 2;
    const size_t O_Q = 0;
    const size_t O_K = SZ_NB;
    const size_t O_V = 2 * SZ_NB;
    const size_t O_FCONV = 3 * SZ_NB;
    const size_t O_CONVOUT = O_FCONV + (size_t)NBATCH * 288 * LL * 2;
    const size_t O_PART = O_CONVOUT + SZ_NB;
    const size_t O_KV = O_PART + (size_t)75 * 32 * 1056 * 4;
    const size_t O_KS = O_KV + (size_t)32 * 1024 * 4;
    const size_t O_WT = O_KS + (size_t)32 * 32 * 4;
    const size_t O_XB = O_WT + 704512 * 2 + 1024;
    const size_t O_SRCB = O_XB + SZ_NB;
    const size_t NEED = O_SRCB + SZ_NB;

    uint16_t* qB      = (uint16_t*)(ws + O_Q);
    uint16_t* kB      = (uint16_t*)(ws + O_K);
    uint16_t* vB      = (uint16_t*)(ws + O_V);
    uint16_t* fconv   = (uint16_t*)(ws + O_FCONV);
    uint16_t* convout = (uint16_t*)(ws + O_CONVOUT);
    float*    part    = (float*)(ws + O_PART);
    float*    KVg     = (float*)(ws + O_KV);
    float*    Ksg     = (float*)(ws + O_KS);
    uint16_t* wt_q    = (uint16_t*)(ws + O_WT);
    uint16_t* wt_k    = wt_q + 256 * 256;
    uint16_t* wt_v    = wt_k + 256 * 256;
    uint16_t* wt_m    = wt_v + 256 * 256;
    uint16_t* wt_m1   = wt_m + 256 * 256;
    uint16_t* wt_m2   = wt_m1 + 512 * 512;
    uint16_t* wt_d    = wt_m2 + 512 * 256;
    uint16_t* wt_u    = wt_d + 512 * 64;
    uint16_t* xb      = (uint16_t*)(ws + O_XB);
    uint16_t* srcb    = (uint16_t*)(ws + O_SRCB);
    // aliases (lifetimes vs launch order):
    uint16_t* msgattn = kB;
    uint16_t* msgB    = vB;
    uint16_t* hidden  = qB;
    uint16_t* msg2    = fconv;
    uint16_t* h2      = (uint16_t*)(ws + O_PART);

    const bool big = ws_size >= NEED;

    prep_all<<<172, 256, 0, stream>>>(Wq, Wk, Wv, Wmerge, Wmlp1, Wmlp2, Wdown, Wup,
                                      wt_q, wt_k, wt_v, wt_m, wt_m1, wt_m2, wt_d, wt_u);

    const dim3 g600(NROWS / 128, 1);
    if (big) {
        conv_bf16<<<dim3(4800, 2), 256, 0, stream>>>(x, src, xb, srcb);
        // --- QKV: pure gll16 pipeline from bf16 copies ---
        gemm_big<256, 256, 0, EPI_NONE, 0><<<g600, 512, 0, stream>>>(nullptr, xb, nullptr, wt_q, qB, nullptr, 256,
            nullptr, nullptr, nullptr, nullptr, nullptr, nullptr, nullptr, nullptr);
        gemm_big<256, 256, 0, EPI_NONE, 0><<<g600, 512, 0, stream>>>(nullptr, srcb, nullptr, wt_k, kB, nullptr, 256,
            nullptr, nullptr, nullptr, nullptr, nullptr, nullptr, nullptr, nullptr);
        gemm_big<256, 256, 0, EPI_NONE, 0><<<g600, 512, 0, stream>>>(nullptr, srcb, nullptr, wt_v, vB, nullptr, 256,
            nullptr, nullptr, nullptr, nullptr, nullptr, nullptr, nullptr, nullptr);
    } else {
        gemm_big<256, 256, 1, EPI_NONE, 0><<<g600, 512, 0, stream>>>(x, nullptr, nullptr, wt_q, qB, nullptr, 256,
            nullptr, nullptr, nullptr, nullptr, nullptr, nullptr, nullptr, nullptr);
        gemm_big<256, 256, 1, EPI_NONE, 0><<<g600, 512, 0, stream>>>(src, nullptr, nullptr, wt_k, kB, nullptr, 256,
            nullptr, nullptr, nullptr, nullptr, nullptr, nullptr, nullptr, nullptr);
        gemm_big<256, 256, 1, EPI_NONE, 0><<<g600, 512, 0, stream>>>(src, nullptr, nullptr, wt_v, vB, nullptr, 256,
            nullptr, nullptr, nullptr, nullptr, nullptr, nullptr, nullptr, nullptr);
    }
    // --- linear attention KV reduce ---
    kv_partial<<<dim3(75, 32), 256, 0, stream>>>(kB, vB, part);
    kv_final<<<32, 256, 0, stream>>>(part, KVg, Ksg);
    // --- conv branch ---
    f9_kernel<<<dim3(LL / 32, NBATCH), 256, 0, stream>>>(qB, kB, vB, fcw, fcb, fconv);
    dwconv2<<<dim3(5, 5, 128), 256, 0, stream>>>(fconv, depw, depb, convout);
    // --- attention message (MFMA; overwrites kB) ---
    attn_mfma<<<NROWS / 64, 256, 0, stream>>>(qB, KVg, Ksg, msgattn);
    // --- merge + LN1 ---
    gemm_big<256, 256, 0, EPI_LN, 0><<<g600, 512, 0, stream>>>(nullptr, msgattn, nullptr, wt_m, msgB, nullptr, 256,
        nullptr, ln1w, ln1b, nullptr, nullptr, nullptr, nullptr, nullptr);
    // --- MLP1 + relu (grid y-fast: both col-blocks of a row adjacent -> A L2 reuse) ---
    if (big) {
        gemm_big<256, 512, 3, EPI_RELU, 1><<<dim3(2, NROWS / 128), 512, 0, stream>>>(nullptr, xb, msgB, wt_m1, hidden, nullptr, 512,
            nullptr, nullptr, nullptr, nullptr, nullptr, nullptr, nullptr, nullptr);
    } else {
        gemm_big<256, 512, 2, EPI_RELU, 0><<<dim3(NROWS / 128, 2), 512, 0, stream>>>(x, nullptr, msgB, wt_m1, hidden, nullptr, 512,
            nullptr, nullptr, nullptr, nullptr, nullptr, nullptr, nullptr, nullptr);
    }
    // --- MLP2 + LN2 ---
    gemm_big<256, 512, 0, EPI_LN, 0><<<g600, 512, 0, stream>>>(nullptr, hidden, nullptr, wt_m2, msg2, nullptr, 256,
        nullptr, ln2w, ln2b, nullptr, nullptr, nullptr, nullptr, nullptr);
    // --- adapter down + relu ---
    if (big) {
        gemm_big<64, 512, 3, EPI_RELU, 0><<<g600, 512, 0, stream>>>(nullptr, xb, msg2, wt_d, h2, nullptr, 64,
            nullptr, nullptr, nullptr, nullptr, nullptr, nullptr, nullptr, nullptr);
    } else {
        gemm_big<64, 512, 2, EPI_RELU, 0><<<g600, 512, 0, stream>>>(x, nullptr, msg2, wt_d, h2, nullptr, 64,
            nullptr, nullptr, nullptr, nullptr, nullptr, nullptr, nullptr, nullptr);
    }
    // --- adapter up + final combine ---
    gemm_big<256, 64, 0, EPI_FINAL, 0><<<g600, 512, 0, stream>>>(nullptr, h2, nullptr, wt_u, nullptr, (float*)d_out, 256,
        nullptr, nullptr, nullptr, x, big ? xb : nullptr, msg2, convout, rate);
}